// Round 4
// baseline (89.274 us; speedup 1.0000x reference)
//
#include <hip/hip_runtime.h>
#include <hip/hip_bf16.h>

#define NAG 8
#define BATCH 32768
#define DDIM 128
#define ADIM 64
#define HDIM 128

#define NJ1 11            // layer1 col tiles: 128 (W1) + 32 (Wc1) + 1 (Ws1) -> 176 cols
#define NJ2 8
#define NJ3 4
#define FB_L1 (NJ1*4)     // 44 frag blocks
#define FB_L2 (NJ2*4)     // 32
#define FB_L3 (NJ3*4)     // 16
#define FB_TOT (FB_L1+FB_L2+FB_L3)  // 92
#define WAGENT (FB_TOT*512)         // 47104 ushort per agent (92KB)

typedef __attribute__((ext_vector_type(8))) short bf16x8;
typedef __attribute__((ext_vector_type(4))) float f32x4;
typedef __attribute__((ext_vector_type(4))) unsigned int u32x4;

static __device__ __forceinline__ unsigned short f2bf(float f) {
  unsigned int u = __builtin_bit_cast(unsigned int, f);
  u += 0x7fffu + ((u >> 16) & 1u);          // RNE (inputs are finite)
  return (unsigned short)(u >> 16);
}

static __device__ __forceinline__ unsigned int cvt_pk_bf16(float a, float b) {
  unsigned int r;
  asm("v_cvt_pk_bf16_f32 %0, %1, %2" : "=v"(r) : "v"(a), "v"(b));
  return r;
}

// ---------------- prep: f32 weights -> bf16 B-fragment-linear layout (proven) ----------------
// frag block fb=(j,kk): 512 bf16; element l*8+t = W[k = kk*32 + (l>>4)*8 + t][col = j*16 + (l&15)]
__global__ void __launch_bounds__(256)
prep_weights(const float* __restrict__ W1, const float* __restrict__ W2,
             const float* __restrict__ W3, const float* __restrict__ Wc1,
             const float* __restrict__ Ws1, const float* __restrict__ b1,
             const float* __restrict__ bc1, const float* __restrict__ bs1,
             unsigned short* __restrict__ wbuf, float* __restrict__ b1e)
{
  int tid = blockIdx.x * 256 + threadIdx.x;
  if (tid < NAG * WAGENT) {
    int agent = tid / WAGENT;
    int rem   = tid % WAGENT;
    int fb = rem >> 9;
    int li = rem & 511;
    int l = li >> 3, t = li & 7;
    int lr = l & 15, lg = l >> 4;
    float v = 0.0f;
    if (fb < FB_L1) {
      int j = fb >> 2, kk = fb & 3;
      int col = j*16 + lr, k = kk*32 + lg*8 + t;
      if (col < 128)       v = W1[((size_t)agent*128 + k)*128 + col];
      else if (col < 160)  v = Wc1[k*32 + (col-128)];
      else if (col == 160) v = Ws1[k];
    } else if (fb < FB_L1 + FB_L2) {
      int f = fb - FB_L1;
      int j = f >> 2, kk = f & 3;
      int col = j*16 + lr, k = kk*32 + lg*8 + t;
      v = W2[((size_t)agent*128 + k)*128 + col];
    } else {
      int f = fb - FB_L1 - FB_L2;
      int j = f >> 2, kk = f & 3;
      int col = j*16 + lr, k = kk*32 + lg*8 + t;
      v = W3[((size_t)agent*128 + k)*64 + col];
    }
    wbuf[tid] = f2bf(v);
  }
  if (tid < NAG * 176) {     // extended layer-1 bias: [b1 | bc1 | bs1 | 0]
    int agent = tid / 176, col = tid % 176;
    float v = 0.0f;
    if (col < 128)       v = b1[agent*128 + col];
    else if (col < 160)  v = bc1[col - 128];
    else if (col == 160) v = bs1[0];
    b1e[tid] = v;
  }
}

// ---------------- main: agent-parallel waves, M=32/wave, 256-thread blocks ----------------
// grid (1024, 2): gid.x = 32-row group, gid.y = agent half (0: agents 0-3, 1: 4-7).
// Wave w handles agent gid.y*4+w. Weights read from global (L2-resident wbuf).
// LDS: 4 x 8KB per-wave h buffer (reused as f32 partial for cross-agent reduce).
// Halves combine via atomicAdd into memset-zeroed out (2 contributors -> deterministic).
// __launch_bounds__(256,4): 4 blocks/CU (16 waves/CU) — pure occupancy lever vs round 3.
__global__ void __launch_bounds__(256, 4)
qatten_main(const float* __restrict__ states,
            const float* __restrict__ b2g, const float* __restrict__ b3g,
            const float* __restrict__ ws2p, const float* __restrict__ bs2p,
            const float* __restrict__ wc2g, const float* __restrict__ bc2p,
            const unsigned short* __restrict__ wbuf,
            const float* __restrict__ b1e,
            float* __restrict__ out)
{
  __shared__ __align__(16) unsigned short hlds[4 * 4096];   // 32 KB

  const int tid  = threadIdx.x;
  const int wave = tid >> 6;
  const int lane = tid & 63;
  const int lr   = lane & 15;
  const int lg   = lane >> 4;
  const int agent = blockIdx.y * 4 + wave;
  const int row0  = blockIdx.x * 32;

  const unsigned short* wag = wbuf + (size_t)agent * WAGENT;
  unsigned short* hp = hlds + wave * 4096;          // this wave's 8KB region

  float b1v[NJ1], b2v[NJ2], b3v[NJ3];
#pragma unroll
  for (int j = 0; j < NJ1; ++j) b1v[j] = b1e[agent*176 + j*16 + lr];
#pragma unroll
  for (int j = 0; j < NJ2; ++j) b2v[j] = b2g[agent*HDIM + j*16 + lr];
#pragma unroll
  for (int j = 0; j < NJ3; ++j) b3v[j] = b3g[agent*ADIM + j*16 + lr];
  const float ws2  = ws2p[0];
  const float bs2v = bs2p[0];
  const float bc2v = bc2p[0];
  const float wc2a = wc2g[lr];
  const float wc2b = wc2g[16 + lr];

  const f32x4 zero4 = {0.f, 0.f, 0.f, 0.f};

  // ---- A1 fragments from global states (f32 -> bf16, 2 m-tiles) ----
  bf16x8 afr[2][4];
  {
    const float* sb = states + ((size_t)agent * BATCH + row0) * DDIM;
#pragma unroll
    for (int m = 0; m < 2; ++m)
#pragma unroll
      for (int kk = 0; kk < 4; ++kk) {
        const float* p = sb + (m*16 + lr)*DDIM + kk*32 + lg*8;
        f32x4 v0 = *(const f32x4*)p;
        f32x4 v1 = *(const f32x4*)(p + 4);
        u32x4 w;
        w[0] = cvt_pk_bf16(v0[0], v0[1]);
        w[1] = cvt_pk_bf16(v0[2], v0[3]);
        w[2] = cvt_pk_bf16(v1[0], v1[1]);
        w[3] = cvt_pk_bf16(v1[2], v1[3]);
        afr[m][kk] = __builtin_bit_cast(bf16x8, w);
      }
  }

  // ---- gate & constraint tiles (j = 8,9,10) ----
  float scl[2][4], crow[2][4];
  {
    f32x4 eacc[3][2];
#pragma unroll
    for (int jx = 0; jx < 3; ++jx) {
      bf16x8 bfr[4];
#pragma unroll
      for (int kk = 0; kk < 4; ++kk)
        bfr[kk] = *(const bf16x8*)&wag[((8+jx)*4 + kk)*512 + lane*8];
#pragma unroll
      for (int m = 0; m < 2; ++m) {
        f32x4 a = zero4;
#pragma unroll
        for (int kk = 0; kk < 4; ++kk)
          a = __builtin_amdgcn_mfma_f32_16x16x32_bf16(afr[m][kk], bfr[kk], a, 0, 0, 0);
        eacc[jx][m] = a;
      }
    }
#pragma unroll
    for (int m = 0; m < 2; ++m) {
#pragma unroll
      for (int r = 0; r < 4; ++r) {
        float c0 = eacc[0][m][r] + b1v[8];  c0 = c0 > 0.f ? c0 : 0.f;
        float c1 = eacc[1][m][r] + b1v[9];  c1 = c1 > 0.f ? c1 : 0.f;
        float cd = c0*wc2a + c1*wc2b;
        cd += __shfl_xor(cd, 1);
        cd += __shfl_xor(cd, 2);
        cd += __shfl_xor(cd, 4);
        cd += __shfl_xor(cd, 8);          // sum over 16 cols within lg-group
        crow[m][r] = cd + bc2v;
        float sp = eacc[2][m][r] + b1v[10];
        sp = __shfl(sp, lane & 48);       // broadcast col-160 (lr==0) value
        sp = sp > 0.f ? sp : 0.f;
        float s = ws2 * sp + bs2v;
        scl[m][r] = 1.f / (1.f + __expf(-s));
      }
    }
  }

  // ---- layer 1 main (j = 0..7) -> h (swizzled row-major [32][128] bf16) ----
#pragma unroll
  for (int j = 0; j < 8; ++j) {
    bf16x8 bfr[4];
#pragma unroll
    for (int kk = 0; kk < 4; ++kk)
      bfr[kk] = *(const bf16x8*)&wag[(j*4 + kk)*512 + lane*8];
#pragma unroll
    for (int m = 0; m < 2; ++m) {
      f32x4 acc = zero4;
#pragma unroll
      for (int kk = 0; kk < 4; ++kk)
        acc = __builtin_amdgcn_mfma_f32_16x16x32_bf16(afr[m][kk], bfr[kk], acc, 0, 0, 0);
#pragma unroll
      for (int r = 0; r < 4; ++r) {
        float hv = acc[r] + b1v[j];
        hv = hv > 0.f ? hv : 0.f;
        int row = m*16 + lg*4 + r;
        int bo = row*256 + (((j*16 + lr)*2) ^ ((row & 7) << 4));   // XOR swizzle
        *(unsigned short*)((char*)hp + bo) = f2bf(hv);
      }
    }
  }

  asm volatile("s_waitcnt lgkmcnt(0)" ::: "memory");
  // ---- A2 fragments from own h region ----
#pragma unroll
  for (int m = 0; m < 2; ++m)
#pragma unroll
    for (int kk = 0; kk < 4; ++kk) {
      int row = m*16 + lr;
      int bo = row*256 + ((kk*64 + lg*16) ^ ((row & 7) << 4));
      afr[m][kk] = *(const bf16x8*)((char*)hp + bo);
    }

  // ---- layer 2 (j = 0..7) ----
#pragma unroll
  for (int j = 0; j < 8; ++j) {
    bf16x8 bfr[4];
#pragma unroll
    for (int kk = 0; kk < 4; ++kk)
      bfr[kk] = *(const bf16x8*)&wag[(FB_L1 + j*4 + kk)*512 + lane*8];
#pragma unroll
    for (int m = 0; m < 2; ++m) {
      f32x4 acc = zero4;
#pragma unroll
      for (int kk = 0; kk < 4; ++kk)
        acc = __builtin_amdgcn_mfma_f32_16x16x32_bf16(afr[m][kk], bfr[kk], acc, 0, 0, 0);
#pragma unroll
      for (int r = 0; r < 4; ++r) {
        float hv = acc[r] + b2v[j];
        hv = hv > 0.f ? hv : 0.f;
        int row = m*16 + lg*4 + r;
        int bo = row*256 + (((j*16 + lr)*2) ^ ((row & 7) << 4));
        *(unsigned short*)((char*)hp + bo) = f2bf(hv);   // overwrite h1
      }
    }
  }

  asm volatile("s_waitcnt lgkmcnt(0)" ::: "memory");
  // ---- A3 fragments from h2 ----
#pragma unroll
  for (int m = 0; m < 2; ++m)
#pragma unroll
    for (int kk = 0; kk < 4; ++kk) {
      int row = m*16 + lr;
      int bo = row*256 + ((kk*64 + lg*16) ^ ((row & 7) << 4));
      afr[m][kk] = *(const bf16x8*)((char*)hp + bo);
    }

  // ---- layer 3 (q), gated, + c folded in ----
  f32x4 out_acc[2][NJ3];
#pragma unroll
  for (int j = 0; j < NJ3; ++j) {
    bf16x8 bfr[4];
#pragma unroll
    for (int kk = 0; kk < 4; ++kk)
      bfr[kk] = *(const bf16x8*)&wag[(FB_L1 + FB_L2 + j*4 + kk)*512 + lane*8];
#pragma unroll
    for (int m = 0; m < 2; ++m) {
      f32x4 acc = zero4;
#pragma unroll
      for (int kk = 0; kk < 4; ++kk)
        acc = __builtin_amdgcn_mfma_f32_16x16x32_bf16(afr[m][kk], bfr[kk], acc, 0, 0, 0);
#pragma unroll
      for (int r = 0; r < 4; ++r)
        out_acc[m][j][r] = scl[m][r] * (acc[r] + b3v[j]) + crow[m][r];
    }
  }

  // ---- dump partial into own region, frag-linear (conflict-free b128) ----
  asm volatile("s_waitcnt lgkmcnt(0)" ::: "memory");  // A3 reads done before overwrite
#pragma unroll
  for (int m = 0; m < 2; ++m)
#pragma unroll
    for (int j = 0; j < NJ3; ++j)
      *(f32x4*)&hp[((m*4 + j)*64 + lane)*8] = out_acc[m][j];

  __syncthreads();

  // ---- cross-wave (4 agents) reduce + atomic combine of the two halves ----
#pragma unroll
  for (int s2 = 0; s2 < 2; ++s2) {
    int s = tid + s2*256;                 // 512 slots of f32x4
    f32x4 sum = zero4;
#pragma unroll
    for (int w = 0; w < 4; ++w) {
      f32x4 v = *(const f32x4*)&hlds[(w*4096) + s*8];
      sum[0] += v[0]; sum[1] += v[1]; sum[2] += v[2]; sum[3] += v[3];
    }
    int mj = s >> 6, ln = s & 63;
    int m = mj >> 2, j = mj & 3;
    int lg2 = ln >> 4, lr2 = ln & 15;
#pragma unroll
    for (int r = 0; r < 4; ++r) {
      int row = row0 + m*16 + lg2*4 + r;
      atomicAdd(&out[(size_t)row*ADIM + j*16 + lr2], sum[r] * 0.125f);
    }
  }
}

extern "C" void kernel_launch(void* const* d_in, const int* in_sizes, int n_in,
                              void* d_out, int out_size, void* d_ws, size_t ws_size,
                              hipStream_t stream)
{
  const float* states = (const float*)d_in[0];
  const float* W1  = (const float*)d_in[1];
  const float* b1  = (const float*)d_in[2];
  const float* W2  = (const float*)d_in[3];
  const float* b2  = (const float*)d_in[4];
  const float* W3  = (const float*)d_in[5];
  const float* b3  = (const float*)d_in[6];
  const float* Ws1 = (const float*)d_in[13];
  const float* bs1 = (const float*)d_in[14];
  const float* Ws2 = (const float*)d_in[15];
  const float* bs2 = (const float*)d_in[16];
  const float* Wc1 = (const float*)d_in[17];
  const float* bc1 = (const float*)d_in[18];
  const float* Wc2 = (const float*)d_in[19];
  const float* bc2 = (const float*)d_in[20];

  unsigned short* wbuf = (unsigned short*)d_ws;
  float* b1e = (float*)((char*)d_ws + (size_t)NAG * WAGENT * 2);

  hipMemsetAsync(d_out, 0, (size_t)out_size * sizeof(float), stream);

  dim3 pb(256), pg((NAG * WAGENT + 255) / 256);
  prep_weights<<<pg, pb, 0, stream>>>(W1, W2, W3, Wc1, Ws1, b1, bc1, bs1, wbuf, b1e);

  dim3 mb(256), mg(BATCH / 32, 2);   // 1024 row-groups x 2 agent halves
  qatten_main<<<mg, mb, 0, stream>>>(states, b2, b3, Ws2, bs2, Wc2, bc2,
                                     wbuf, b1e, (float*)d_out);
}

// Round 5
// 80.771 us; speedup vs baseline: 1.1053x; 1.1053x over previous
//
#include <hip/hip_runtime.h>
#include <hip/hip_bf16.h>

#define NAG 8
#define BATCH 32768
#define DDIM 128
#define ADIM 64
#define HDIM 128

#define NJ1 11            // layer1 col tiles: 128 (W1) + 32 (Wc1) + 1 (Ws1) -> 176 cols
#define NJ2 8
#define NJ3 4
#define FB_L1 (NJ1*4)     // 44 frag blocks
#define FB_L2 (NJ2*4)     // 32
#define FB_L3 (NJ3*4)     // 16
#define FB_TOT (FB_L1+FB_L2+FB_L3)  // 92
#define WAGENT (FB_TOT*512)         // 47104 ushort per agent (92KB)

typedef __attribute__((ext_vector_type(8))) short bf16x8;
typedef __attribute__((ext_vector_type(4))) float f32x4;
typedef __attribute__((ext_vector_type(4))) unsigned int u32x4;

static __device__ __forceinline__ unsigned short f2bf(float f) {
  unsigned int u = __builtin_bit_cast(unsigned int, f);
  u += 0x7fffu + ((u >> 16) & 1u);          // RNE (inputs are finite)
  return (unsigned short)(u >> 16);
}

static __device__ __forceinline__ unsigned int cvt_pk_bf16(float a, float b) {
  unsigned int r;
  asm("v_cvt_pk_bf16_f32 %0, %1, %2" : "=v"(r) : "v"(a), "v"(b));
  return r;
}

// ---------------- prep: f32 weights -> bf16 B-fragment-linear layout (proven) ----------------
// frag block fb=(j,kk): 512 bf16; element l*8+t = W[k = kk*32 + (l>>4)*8 + t][col = j*16 + (l&15)]
__global__ void __launch_bounds__(256)
prep_weights(const float* __restrict__ W1, const float* __restrict__ W2,
             const float* __restrict__ W3, const float* __restrict__ Wc1,
             const float* __restrict__ Ws1, const float* __restrict__ b1,
             const float* __restrict__ bc1, const float* __restrict__ bs1,
             unsigned short* __restrict__ wbuf, float* __restrict__ b1e)
{
  int tid = blockIdx.x * 256 + threadIdx.x;
  if (tid < NAG * WAGENT) {
    int agent = tid / WAGENT;
    int rem   = tid % WAGENT;
    int fb = rem >> 9;
    int li = rem & 511;
    int l = li >> 3, t = li & 7;
    int lr = l & 15, lg = l >> 4;
    float v = 0.0f;
    if (fb < FB_L1) {
      int j = fb >> 2, kk = fb & 3;
      int col = j*16 + lr, k = kk*32 + lg*8 + t;
      if (col < 128)       v = W1[((size_t)agent*128 + k)*128 + col];
      else if (col < 160)  v = Wc1[k*32 + (col-128)];
      else if (col == 160) v = Ws1[k];
    } else if (fb < FB_L1 + FB_L2) {
      int f = fb - FB_L1;
      int j = f >> 2, kk = f & 3;
      int col = j*16 + lr, k = kk*32 + lg*8 + t;
      v = W2[((size_t)agent*128 + k)*128 + col];
    } else {
      int f = fb - FB_L1 - FB_L2;
      int j = f >> 2, kk = f & 3;
      int col = j*16 + lr, k = kk*32 + lg*8 + t;
      v = W3[((size_t)agent*128 + k)*64 + col];
    }
    wbuf[tid] = f2bf(v);
  }
  if (tid < NAG * 176) {     // extended layer-1 bias: [b1 | bc1 | bs1 | 0]
    int agent = tid / 176, col = tid % 176;
    float v = 0.0f;
    if (col < 128)       v = b1[agent*128 + col];
    else if (col < 160)  v = bc1[col - 128];
    else if (col == 160) v = bs1[0];
    b1e[tid] = v;
  }
}

// ---------------- main: agent-parallel waves, M=64/wave, 256-thread blocks ----------------
// grid (512, 2): gid.x = 64-row group, gid.y = agent half (0: agents 0-3, 1: 4-7).
// Wave w handles agent gid.y*4+w. Weights read from global (L2-resident wbuf),
// each 92KB weight stream amortized over 64 rows (16 MFMA per 4-load group).
// LDS: 4 x 16KB per-wave h buffer (reused as f32 partial for cross-agent reduce).
// Halves combine via atomicAdd into memset-zeroed out (2 contributors -> deterministic).
__global__ void __launch_bounds__(256, 2)
qatten_main(const float* __restrict__ states,
            const float* __restrict__ b2g, const float* __restrict__ b3g,
            const float* __restrict__ ws2p, const float* __restrict__ bs2p,
            const float* __restrict__ wc2g, const float* __restrict__ bc2p,
            const unsigned short* __restrict__ wbuf,
            const float* __restrict__ b1e,
            float* __restrict__ out)
{
  __shared__ __align__(16) unsigned short hlds[4 * 8192];   // 64 KB

  const int tid  = threadIdx.x;
  const int wave = tid >> 6;
  const int lane = tid & 63;
  const int lr   = lane & 15;
  const int lg   = lane >> 4;
  const int agent = blockIdx.y * 4 + wave;
  const int row0  = blockIdx.x * 64;

  const unsigned short* wag = wbuf + (size_t)agent * WAGENT;
  unsigned short* hp = hlds + wave * 8192;          // this wave's 16KB region

  float b1v[NJ1], b2v[NJ2], b3v[NJ3];
#pragma unroll
  for (int j = 0; j < NJ1; ++j) b1v[j] = b1e[agent*176 + j*16 + lr];
#pragma unroll
  for (int j = 0; j < NJ2; ++j) b2v[j] = b2g[agent*HDIM + j*16 + lr];
#pragma unroll
  for (int j = 0; j < NJ3; ++j) b3v[j] = b3g[agent*ADIM + j*16 + lr];
  const float ws2  = ws2p[0];
  const float bs2v = bs2p[0];
  const float bc2v = bc2p[0];
  const float wc2a = wc2g[lr];
  const float wc2b = wc2g[16 + lr];

  const f32x4 zero4 = {0.f, 0.f, 0.f, 0.f};

  // ---- A1 fragments from global states (f32 -> bf16, 4 m-tiles = 64 rows) ----
  bf16x8 afr[4][4];
  {
    const float* sb = states + ((size_t)agent * BATCH + row0) * DDIM;
#pragma unroll
    for (int m = 0; m < 4; ++m)
#pragma unroll
      for (int kk = 0; kk < 4; ++kk) {
        const float* p = sb + (m*16 + lr)*DDIM + kk*32 + lg*8;
        f32x4 v0 = *(const f32x4*)p;
        f32x4 v1 = *(const f32x4*)(p + 4);
        u32x4 w;
        w[0] = cvt_pk_bf16(v0[0], v0[1]);
        w[1] = cvt_pk_bf16(v0[2], v0[3]);
        w[2] = cvt_pk_bf16(v1[0], v1[1]);
        w[3] = cvt_pk_bf16(v1[2], v1[3]);
        afr[m][kk] = __builtin_bit_cast(bf16x8, w);
      }
  }

  // ---- gate & constraint tiles (j = 8,9,10) ----
  float scl[4][4], crow[4][4];
  {
    f32x4 eacc[3][4];
#pragma unroll
    for (int jx = 0; jx < 3; ++jx) {
      bf16x8 bfr[4];
#pragma unroll
      for (int kk = 0; kk < 4; ++kk)
        bfr[kk] = *(const bf16x8*)&wag[((8+jx)*4 + kk)*512 + lane*8];
#pragma unroll
      for (int m = 0; m < 4; ++m) {
        f32x4 a = zero4;
#pragma unroll
        for (int kk = 0; kk < 4; ++kk)
          a = __builtin_amdgcn_mfma_f32_16x16x32_bf16(afr[m][kk], bfr[kk], a, 0, 0, 0);
        eacc[jx][m] = a;
      }
    }
#pragma unroll
    for (int m = 0; m < 4; ++m) {
#pragma unroll
      for (int r = 0; r < 4; ++r) {
        float c0 = eacc[0][m][r] + b1v[8];  c0 = c0 > 0.f ? c0 : 0.f;
        float c1 = eacc[1][m][r] + b1v[9];  c1 = c1 > 0.f ? c1 : 0.f;
        float cd = c0*wc2a + c1*wc2b;
        cd += __shfl_xor(cd, 1);
        cd += __shfl_xor(cd, 2);
        cd += __shfl_xor(cd, 4);
        cd += __shfl_xor(cd, 8);          // sum over 16 cols within lg-group
        crow[m][r] = cd + bc2v;
        float sp = eacc[2][m][r] + b1v[10];
        sp = __shfl(sp, lane & 48);       // broadcast col-160 (lr==0) value
        sp = sp > 0.f ? sp : 0.f;
        float s = ws2 * sp + bs2v;
        scl[m][r] = 1.f / (1.f + __expf(-s));
      }
    }
  }

  // ---- layer 1 main (j = 0..7) -> h (swizzled row-major [64][128] bf16) ----
#pragma unroll
  for (int j = 0; j < 8; ++j) {
    bf16x8 bfr[4];
#pragma unroll
    for (int kk = 0; kk < 4; ++kk)
      bfr[kk] = *(const bf16x8*)&wag[(j*4 + kk)*512 + lane*8];
#pragma unroll
    for (int m = 0; m < 4; ++m) {
      f32x4 acc = zero4;
#pragma unroll
      for (int kk = 0; kk < 4; ++kk)
        acc = __builtin_amdgcn_mfma_f32_16x16x32_bf16(afr[m][kk], bfr[kk], acc, 0, 0, 0);
#pragma unroll
      for (int r = 0; r < 4; ++r) {
        float hv = acc[r] + b1v[j];
        hv = hv > 0.f ? hv : 0.f;
        int row = m*16 + lg*4 + r;
        int bo = row*256 + (((j*16 + lr)*2) ^ ((row & 7) << 4));   // XOR swizzle
        *(unsigned short*)((char*)hp + bo) = f2bf(hv);
      }
    }
  }

  asm volatile("s_waitcnt lgkmcnt(0)" ::: "memory");
  // ---- A2 fragments from own h region ----
#pragma unroll
  for (int m = 0; m < 4; ++m)
#pragma unroll
    for (int kk = 0; kk < 4; ++kk) {
      int row = m*16 + lr;
      int bo = row*256 + ((kk*64 + lg*16) ^ ((row & 7) << 4));
      afr[m][kk] = *(const bf16x8*)((char*)hp + bo);
    }

  // ---- layer 2 (j = 0..7) ----
#pragma unroll
  for (int j = 0; j < 8; ++j) {
    bf16x8 bfr[4];
#pragma unroll
    for (int kk = 0; kk < 4; ++kk)
      bfr[kk] = *(const bf16x8*)&wag[(FB_L1 + j*4 + kk)*512 + lane*8];
#pragma unroll
    for (int m = 0; m < 4; ++m) {
      f32x4 acc = zero4;
#pragma unroll
      for (int kk = 0; kk < 4; ++kk)
        acc = __builtin_amdgcn_mfma_f32_16x16x32_bf16(afr[m][kk], bfr[kk], acc, 0, 0, 0);
#pragma unroll
      for (int r = 0; r < 4; ++r) {
        float hv = acc[r] + b2v[j];
        hv = hv > 0.f ? hv : 0.f;
        int row = m*16 + lg*4 + r;
        int bo = row*256 + (((j*16 + lr)*2) ^ ((row & 7) << 4));
        *(unsigned short*)((char*)hp + bo) = f2bf(hv);   // overwrite h1
      }
    }
  }

  asm volatile("s_waitcnt lgkmcnt(0)" ::: "memory");
  // ---- A3 fragments from h2 ----
#pragma unroll
  for (int m = 0; m < 4; ++m)
#pragma unroll
    for (int kk = 0; kk < 4; ++kk) {
      int row = m*16 + lr;
      int bo = row*256 + ((kk*64 + lg*16) ^ ((row & 7) << 4));
      afr[m][kk] = *(const bf16x8*)((char*)hp + bo);
    }
  asm volatile("s_waitcnt lgkmcnt(0)" ::: "memory");   // A3 in regs before dump overwrites h

  // ---- layer 3 (q): gate + c fused, direct LDS partial dump (no out_acc array) ----
#pragma unroll
  for (int j = 0; j < NJ3; ++j) {
    bf16x8 bfr[4];
#pragma unroll
    for (int kk = 0; kk < 4; ++kk)
      bfr[kk] = *(const bf16x8*)&wag[(FB_L1 + FB_L2 + j*4 + kk)*512 + lane*8];
#pragma unroll
    for (int m = 0; m < 4; ++m) {
      f32x4 acc = zero4;
#pragma unroll
      for (int kk = 0; kk < 4; ++kk)
        acc = __builtin_amdgcn_mfma_f32_16x16x32_bf16(afr[m][kk], bfr[kk], acc, 0, 0, 0);
      f32x4 o;
#pragma unroll
      for (int r = 0; r < 4; ++r)
        o[r] = scl[m][r] * (acc[r] + b3v[j]) + crow[m][r];
      *(f32x4*)&hp[((m*4 + j)*64 + lane)*8] = o;   // frag-linear, conflict-free b128
    }
  }

  __syncthreads();

  // ---- cross-wave (4 agents) reduce + atomic combine of the two halves ----
#pragma unroll
  for (int s2 = 0; s2 < 4; ++s2) {
    int s = tid + s2*256;                 // 1024 slots of f32x4
    f32x4 sum = zero4;
#pragma unroll
    for (int w = 0; w < 4; ++w) {
      f32x4 v = *(const f32x4*)&hlds[(w*8192) + s*8];
      sum[0] += v[0]; sum[1] += v[1]; sum[2] += v[2]; sum[3] += v[3];
    }
    int mj = s >> 6, ln = s & 63;
    int m = mj >> 2, j = mj & 3;
    int lg2 = ln >> 4, lr2 = ln & 15;
#pragma unroll
    for (int r = 0; r < 4; ++r) {
      int row = row0 + m*16 + lg2*4 + r;
      atomicAdd(&out[(size_t)row*ADIM + j*16 + lr2], sum[r] * 0.125f);
    }
  }
}

extern "C" void kernel_launch(void* const* d_in, const int* in_sizes, int n_in,
                              void* d_out, int out_size, void* d_ws, size_t ws_size,
                              hipStream_t stream)
{
  const float* states = (const float*)d_in[0];
  const float* W1  = (const float*)d_in[1];
  const float* b1  = (const float*)d_in[2];
  const float* W2  = (const float*)d_in[3];
  const float* b2  = (const float*)d_in[4];
  const float* W3  = (const float*)d_in[5];
  const float* b3  = (const float*)d_in[6];
  const float* Ws1 = (const float*)d_in[13];
  const float* bs1 = (const float*)d_in[14];
  const float* Ws2 = (const float*)d_in[15];
  const float* bs2 = (const float*)d_in[16];
  const float* Wc1 = (const float*)d_in[17];
  const float* bc1 = (const float*)d_in[18];
  const float* Wc2 = (const float*)d_in[19];
  const float* bc2 = (const float*)d_in[20];

  unsigned short* wbuf = (unsigned short*)d_ws;
  float* b1e = (float*)((char*)d_ws + (size_t)NAG * WAGENT * 2);

  hipMemsetAsync(d_out, 0, (size_t)out_size * sizeof(float), stream);

  dim3 pb(256), pg((NAG * WAGENT + 255) / 256);
  prep_weights<<<pg, pb, 0, stream>>>(W1, W2, W3, Wc1, Ws1, b1, bc1, bs1, wbuf, b1e);

  dim3 mb(256), mg(BATCH / 64, 2);   // 512 row-groups x 2 agent halves
  qatten_main<<<mg, mb, 0, stream>>>(states, b2, b3, Ws2, bs2, Wc2, bc2,
                                     wbuf, b1e, (float*)d_out);
}

// Round 6
// 67.299 us; speedup vs baseline: 1.3265x; 1.2002x over previous
//
#include <hip/hip_runtime.h>
#include <hip/hip_bf16.h>

#define NAG 8
#define BATCH 32768
#define DDIM 128
#define ADIM 64
#define HDIM 128

#define NJ1 11            // layer1 col tiles: 128 (W1) + 32 (Wc1) + 1 (Ws1) -> 176 cols
#define NJ2 8
#define NJ3 4
#define FB_L1 (NJ1*4)     // 44 frag blocks
#define FB_L2 (NJ2*4)     // 32
#define FB_L3 (NJ3*4)     // 16
#define FB_TOT (FB_L1+FB_L2+FB_L3)  // 92
#define WAGENT (FB_TOT*512)         // 47104 ushort per agent (92KB)

typedef __attribute__((ext_vector_type(8))) short bf16x8;
typedef __attribute__((ext_vector_type(4))) float f32x4;
typedef __attribute__((ext_vector_type(4))) unsigned int u32x4;

static __device__ __forceinline__ unsigned short f2bf(float f) {
  unsigned int u = __builtin_bit_cast(unsigned int, f);
  u += 0x7fffu + ((u >> 16) & 1u);          // RNE (inputs are finite)
  return (unsigned short)(u >> 16);
}

static __device__ __forceinline__ unsigned int cvt_pk_bf16(float a, float b) {
  unsigned int r;
  asm("v_cvt_pk_bf16_f32 %0, %1, %2" : "=v"(r) : "v"(a), "v"(b));
  return r;
}

// ---------------- prep: f32 weights -> bf16 B-fragment-linear layout (proven) ----------------
// frag block fb=(j,kk): 512 bf16; element l*8+t = W[k = kk*32 + (l>>4)*8 + t][col = j*16 + (l&15)]
__global__ void __launch_bounds__(256)
prep_weights(const float* __restrict__ W1, const float* __restrict__ W2,
             const float* __restrict__ W3, const float* __restrict__ Wc1,
             const float* __restrict__ Ws1, const float* __restrict__ b1,
             const float* __restrict__ bc1, const float* __restrict__ bs1,
             unsigned short* __restrict__ wbuf, float* __restrict__ b1e)
{
  int tid = blockIdx.x * 256 + threadIdx.x;
  if (tid < NAG * WAGENT) {
    int agent = tid / WAGENT;
    int rem   = tid % WAGENT;
    int fb = rem >> 9;
    int li = rem & 511;
    int l = li >> 3, t = li & 7;
    int lr = l & 15, lg = l >> 4;
    float v = 0.0f;
    if (fb < FB_L1) {
      int j = fb >> 2, kk = fb & 3;
      int col = j*16 + lr, k = kk*32 + lg*8 + t;
      if (col < 128)       v = W1[((size_t)agent*128 + k)*128 + col];
      else if (col < 160)  v = Wc1[k*32 + (col-128)];
      else if (col == 160) v = Ws1[k];
    } else if (fb < FB_L1 + FB_L2) {
      int f = fb - FB_L1;
      int j = f >> 2, kk = f & 3;
      int col = j*16 + lr, k = kk*32 + lg*8 + t;
      v = W2[((size_t)agent*128 + k)*128 + col];
    } else {
      int f = fb - FB_L1 - FB_L2;
      int j = f >> 2, kk = f & 3;
      int col = j*16 + lr, k = kk*32 + lg*8 + t;
      v = W3[((size_t)agent*128 + k)*64 + col];
    }
    wbuf[tid] = f2bf(v);
  }
  if (tid < NAG * 176) {     // extended layer-1 bias: [b1 | bc1 | bs1 | 0]
    int agent = tid / 176, col = tid % 176;
    float v = 0.0f;
    if (col < 128)       v = b1[agent*128 + col];
    else if (col < 160)  v = bc1[col - 128];
    else if (col == 160) v = bs1[0];
    b1e[tid] = v;
  }
}

// ---------------- main: agent-parallel waves, M=32/wave, 256-thread blocks ----------------
// grid (1024, 2): gid.x = 32-row group, gid.y = agent half (0: agents 0-3, 1: 4-7).
// Wave w handles agent gid.y*4+w. Weights read from global (L2-resident wbuf).
// LDS: 4 x 8KB per-wave h buffer (reused as f32 partial for cross-agent reduce).
// Halves combine via atomicAdd into memset-zeroed out (2 contributors -> deterministic).
// Occupancy metadata: raw attributes instead of __launch_bounds__ — empirically,
// launch_bounds arg N caps BOTH vgpr budget (~256/N) and residency (~N blocks/CU).
// waves_per_eu(2) keeps a >=256-reg budget (no spill at demand ~112) while leaving
// residency resource-limited (VGPR 112 -> 4 waves/EU, LDS 32KB -> 5 blocks/CU).
__global__ void
__attribute__((amdgpu_flat_work_group_size(256, 256)))
__attribute__((amdgpu_waves_per_eu(2)))
qatten_main(const float* __restrict__ states,
            const float* __restrict__ b2g, const float* __restrict__ b3g,
            const float* __restrict__ ws2p, const float* __restrict__ bs2p,
            const float* __restrict__ wc2g, const float* __restrict__ bc2p,
            const unsigned short* __restrict__ wbuf,
            const float* __restrict__ b1e,
            float* __restrict__ out)
{
  __shared__ __align__(16) unsigned short hlds[4 * 4096];   // 32 KB

  const int tid  = threadIdx.x;
  const int wave = tid >> 6;
  const int lane = tid & 63;
  const int lr   = lane & 15;
  const int lg   = lane >> 4;
  const int agent = blockIdx.y * 4 + wave;
  const int row0  = blockIdx.x * 32;

  const unsigned short* wag = wbuf + (size_t)agent * WAGENT;
  unsigned short* hp = hlds + wave * 4096;          // this wave's 8KB region

  float b1v[NJ1], b2v[NJ2], b3v[NJ3];
#pragma unroll
  for (int j = 0; j < NJ1; ++j) b1v[j] = b1e[agent*176 + j*16 + lr];
#pragma unroll
  for (int j = 0; j < NJ2; ++j) b2v[j] = b2g[agent*HDIM + j*16 + lr];
#pragma unroll
  for (int j = 0; j < NJ3; ++j) b3v[j] = b3g[agent*ADIM + j*16 + lr];
  const float ws2  = ws2p[0];
  const float bs2v = bs2p[0];
  const float bc2v = bc2p[0];
  const float wc2a = wc2g[lr];
  const float wc2b = wc2g[16 + lr];

  const f32x4 zero4 = {0.f, 0.f, 0.f, 0.f};

  // ---- A1 fragments from global states (f32 -> bf16, 2 m-tiles) ----
  bf16x8 afr[2][4];
  {
    const float* sb = states + ((size_t)agent * BATCH + row0) * DDIM;
#pragma unroll
    for (int m = 0; m < 2; ++m)
#pragma unroll
      for (int kk = 0; kk < 4; ++kk) {
        const float* p = sb + (m*16 + lr)*DDIM + kk*32 + lg*8;
        f32x4 v0 = *(const f32x4*)p;
        f32x4 v1 = *(const f32x4*)(p + 4);
        u32x4 w;
        w[0] = cvt_pk_bf16(v0[0], v0[1]);
        w[1] = cvt_pk_bf16(v0[2], v0[3]);
        w[2] = cvt_pk_bf16(v1[0], v1[1]);
        w[3] = cvt_pk_bf16(v1[2], v1[3]);
        afr[m][kk] = __builtin_bit_cast(bf16x8, w);
      }
  }

  // ---- gate & constraint tiles (j = 8,9,10) ----
  float scl[2][4], crow[2][4];
  {
    f32x4 eacc[3][2];
#pragma unroll
    for (int jx = 0; jx < 3; ++jx) {
      bf16x8 bfr[4];
#pragma unroll
      for (int kk = 0; kk < 4; ++kk)
        bfr[kk] = *(const bf16x8*)&wag[((8+jx)*4 + kk)*512 + lane*8];
#pragma unroll
      for (int m = 0; m < 2; ++m) {
        f32x4 a = zero4;
#pragma unroll
        for (int kk = 0; kk < 4; ++kk)
          a = __builtin_amdgcn_mfma_f32_16x16x32_bf16(afr[m][kk], bfr[kk], a, 0, 0, 0);
        eacc[jx][m] = a;
      }
    }
#pragma unroll
    for (int m = 0; m < 2; ++m) {
#pragma unroll
      for (int r = 0; r < 4; ++r) {
        float c0 = eacc[0][m][r] + b1v[8];  c0 = c0 > 0.f ? c0 : 0.f;
        float c1 = eacc[1][m][r] + b1v[9];  c1 = c1 > 0.f ? c1 : 0.f;
        float cd = c0*wc2a + c1*wc2b;
        cd += __shfl_xor(cd, 1);
        cd += __shfl_xor(cd, 2);
        cd += __shfl_xor(cd, 4);
        cd += __shfl_xor(cd, 8);          // sum over 16 cols within lg-group
        crow[m][r] = cd + bc2v;
        float sp = eacc[2][m][r] + b1v[10];
        sp = __shfl(sp, lane & 48);       // broadcast col-160 (lr==0) value
        sp = sp > 0.f ? sp : 0.f;
        float s = ws2 * sp + bs2v;
        scl[m][r] = 1.f / (1.f + __expf(-s));
      }
    }
  }

  // ---- layer 1 main (j = 0..7) -> h (swizzled row-major [32][128] bf16) ----
#pragma unroll
  for (int j = 0; j < 8; ++j) {
    bf16x8 bfr[4];
#pragma unroll
    for (int kk = 0; kk < 4; ++kk)
      bfr[kk] = *(const bf16x8*)&wag[(j*4 + kk)*512 + lane*8];
#pragma unroll
    for (int m = 0; m < 2; ++m) {
      f32x4 acc = zero4;
#pragma unroll
      for (int kk = 0; kk < 4; ++kk)
        acc = __builtin_amdgcn_mfma_f32_16x16x32_bf16(afr[m][kk], bfr[kk], acc, 0, 0, 0);
#pragma unroll
      for (int r = 0; r < 4; ++r) {
        float hv = acc[r] + b1v[j];
        hv = hv > 0.f ? hv : 0.f;
        int row = m*16 + lg*4 + r;
        int bo = row*256 + (((j*16 + lr)*2) ^ ((row & 7) << 4));   // XOR swizzle
        *(unsigned short*)((char*)hp + bo) = f2bf(hv);
      }
    }
  }

  asm volatile("s_waitcnt lgkmcnt(0)" ::: "memory");
  // ---- A2 fragments from own h region ----
#pragma unroll
  for (int m = 0; m < 2; ++m)
#pragma unroll
    for (int kk = 0; kk < 4; ++kk) {
      int row = m*16 + lr;
      int bo = row*256 + ((kk*64 + lg*16) ^ ((row & 7) << 4));
      afr[m][kk] = *(const bf16x8*)((char*)hp + bo);
    }

  // ---- layer 2 (j = 0..7) ----
#pragma unroll
  for (int j = 0; j < 8; ++j) {
    bf16x8 bfr[4];
#pragma unroll
    for (int kk = 0; kk < 4; ++kk)
      bfr[kk] = *(const bf16x8*)&wag[(FB_L1 + j*4 + kk)*512 + lane*8];
#pragma unroll
    for (int m = 0; m < 2; ++m) {
      f32x4 acc = zero4;
#pragma unroll
      for (int kk = 0; kk < 4; ++kk)
        acc = __builtin_amdgcn_mfma_f32_16x16x32_bf16(afr[m][kk], bfr[kk], acc, 0, 0, 0);
#pragma unroll
      for (int r = 0; r < 4; ++r) {
        float hv = acc[r] + b2v[j];
        hv = hv > 0.f ? hv : 0.f;
        int row = m*16 + lg*4 + r;
        int bo = row*256 + (((j*16 + lr)*2) ^ ((row & 7) << 4));
        *(unsigned short*)((char*)hp + bo) = f2bf(hv);   // overwrite h1
      }
    }
  }

  asm volatile("s_waitcnt lgkmcnt(0)" ::: "memory");
  // ---- A3 fragments from h2 ----
#pragma unroll
  for (int m = 0; m < 2; ++m)
#pragma unroll
    for (int kk = 0; kk < 4; ++kk) {
      int row = m*16 + lr;
      int bo = row*256 + ((kk*64 + lg*16) ^ ((row & 7) << 4));
      afr[m][kk] = *(const bf16x8*)((char*)hp + bo);
    }

  // ---- layer 3 (q), gated, + c folded in ----
  f32x4 out_acc[2][NJ3];
#pragma unroll
  for (int j = 0; j < NJ3; ++j) {
    bf16x8 bfr[4];
#pragma unroll
    for (int kk = 0; kk < 4; ++kk)
      bfr[kk] = *(const bf16x8*)&wag[(FB_L1 + FB_L2 + j*4 + kk)*512 + lane*8];
#pragma unroll
    for (int m = 0; m < 2; ++m) {
      f32x4 acc = zero4;
#pragma unroll
      for (int kk = 0; kk < 4; ++kk)
        acc = __builtin_amdgcn_mfma_f32_16x16x32_bf16(afr[m][kk], bfr[kk], acc, 0, 0, 0);
#pragma unroll
      for (int r = 0; r < 4; ++r)
        out_acc[m][j][r] = scl[m][r] * (acc[r] + b3v[j]) + crow[m][r];
    }
  }

  // ---- dump partial into own region, frag-linear (conflict-free b128) ----
  asm volatile("s_waitcnt lgkmcnt(0)" ::: "memory");  // A3 reads done before overwrite
#pragma unroll
  for (int m = 0; m < 2; ++m)
#pragma unroll
    for (int j = 0; j < NJ3; ++j)
      *(f32x4*)&hp[((m*4 + j)*64 + lane)*8] = out_acc[m][j];

  __syncthreads();

  // ---- cross-wave (4 agents) reduce + atomic combine of the two halves ----
#pragma unroll
  for (int s2 = 0; s2 < 2; ++s2) {
    int s = tid + s2*256;                 // 512 slots of f32x4
    f32x4 sum = zero4;
#pragma unroll
    for (int w = 0; w < 4; ++w) {
      f32x4 v = *(const f32x4*)&hlds[(w*4096) + s*8];
      sum[0] += v[0]; sum[1] += v[1]; sum[2] += v[2]; sum[3] += v[3];
    }
    int mj = s >> 6, ln = s & 63;
    int m = mj >> 2, j = mj & 3;
    int lg2 = ln >> 4, lr2 = ln & 15;
#pragma unroll
    for (int r = 0; r < 4; ++r) {
      int row = row0 + m*16 + lg2*4 + r;
      atomicAdd(&out[(size_t)row*ADIM + j*16 + lr2], sum[r] * 0.125f);
    }
  }
}

extern "C" void kernel_launch(void* const* d_in, const int* in_sizes, int n_in,
                              void* d_out, int out_size, void* d_ws, size_t ws_size,
                              hipStream_t stream)
{
  const float* states = (const float*)d_in[0];
  const float* W1  = (const float*)d_in[1];
  const float* b1  = (const float*)d_in[2];
  const float* W2  = (const float*)d_in[3];
  const float* b2  = (const float*)d_in[4];
  const float* W3  = (const float*)d_in[5];
  const float* b3  = (const float*)d_in[6];
  const float* Ws1 = (const float*)d_in[13];
  const float* bs1 = (const float*)d_in[14];
  const float* Ws2 = (const float*)d_in[15];
  const float* bs2 = (const float*)d_in[16];
  const float* Wc1 = (const float*)d_in[17];
  const float* bc1 = (const float*)d_in[18];
  const float* Wc2 = (const float*)d_in[19];
  const float* bc2 = (const float*)d_in[20];

  unsigned short* wbuf = (unsigned short*)d_ws;
  float* b1e = (float*)((char*)d_ws + (size_t)NAG * WAGENT * 2);

  hipMemsetAsync(d_out, 0, (size_t)out_size * sizeof(float), stream);

  dim3 pb(256), pg((NAG * WAGENT + 255) / 256);
  prep_weights<<<pg, pb, 0, stream>>>(W1, W2, W3, Wc1, Ws1, b1, bc1, bs1, wbuf, b1e);

  dim3 mb(256), mg(BATCH / 32, 2);   // 1024 row-groups x 2 agent halves
  qatten_main<<<mg, mb, 0, stream>>>(states, b2, b3, Ws2, bs2, Wc2, bc2,
                                     wbuf, b1e, (float*)d_out);
}

// Round 7
// 67.234 us; speedup vs baseline: 1.3278x; 1.0010x over previous
//
#include <hip/hip_runtime.h>
#include <hip/hip_bf16.h>

#define NAG 8
#define BATCH 32768
#define DDIM 128
#define ADIM 64
#define HDIM 128

#define NJ1 11            // layer1 col tiles: 128 (W1) + 32 (Wc1) + 1 (Ws1) -> 176 cols
#define NJ2 8
#define NJ3 4
#define FB_L1 (NJ1*4)     // 44 frag blocks (44KB)
#define FB_L2 (NJ2*4)     // 32
#define FB_L3 (NJ3*4)     // 16
#define FB_TOT (FB_L1+FB_L2+FB_L3)  // 92
#define WAGENT (FB_TOT*512)         // 47104 ushort per agent (92KB)
#define NV_L1 (FB_L1*64)  // 2816 u32x4 elements in layer1 block
#define NV_L23 ((FB_L2+FB_L3)*64)   // 3072 u32x4 elements in layer2+3 block

typedef __attribute__((ext_vector_type(8))) short bf16x8;
typedef __attribute__((ext_vector_type(4))) float f32x4;
typedef __attribute__((ext_vector_type(4))) unsigned int u32x4;

static __device__ __forceinline__ unsigned short f2bf(float f) {
  unsigned int u = __builtin_bit_cast(unsigned int, f);
  u += 0x7fffu + ((u >> 16) & 1u);          // RNE (inputs are finite)
  return (unsigned short)(u >> 16);
}

static __device__ __forceinline__ unsigned int cvt_pk_bf16(float a, float b) {
  unsigned int r;
  asm("v_cvt_pk_bf16_f32 %0, %1, %2" : "=v"(r) : "v"(a), "v"(b));
  return r;
}

// ---------------- prep: f32 weights -> bf16 B-fragment-linear layout (proven) ----------------
// frag block fb=(j,kk): 512 bf16; element l*8+t = W[k = kk*32 + (l>>4)*8 + t][col = j*16 + (l&15)]
__global__ void __launch_bounds__(256)
prep_weights(const float* __restrict__ W1, const float* __restrict__ W2,
             const float* __restrict__ W3, const float* __restrict__ Wc1,
             const float* __restrict__ Ws1, const float* __restrict__ b1,
             const float* __restrict__ bc1, const float* __restrict__ bs1,
             unsigned short* __restrict__ wbuf, float* __restrict__ b1e)
{
  int tid = blockIdx.x * 256 + threadIdx.x;
  if (tid < NAG * WAGENT) {
    int agent = tid / WAGENT;
    int rem   = tid % WAGENT;
    int fb = rem >> 9;
    int li = rem & 511;
    int l = li >> 3, t = li & 7;
    int lr = l & 15, lg = l >> 4;
    float v = 0.0f;
    if (fb < FB_L1) {
      int j = fb >> 2, kk = fb & 3;
      int col = j*16 + lr, k = kk*32 + lg*8 + t;
      if (col < 128)       v = W1[((size_t)agent*128 + k)*128 + col];
      else if (col < 160)  v = Wc1[k*32 + (col-128)];
      else if (col == 160) v = Ws1[k];
    } else if (fb < FB_L1 + FB_L2) {
      int f = fb - FB_L1;
      int j = f >> 2, kk = f & 3;
      int col = j*16 + lr, k = kk*32 + lg*8 + t;
      v = W2[((size_t)agent*128 + k)*128 + col];
    } else {
      int f = fb - FB_L1 - FB_L2;
      int j = f >> 2, kk = f & 3;
      int col = j*16 + lr, k = kk*32 + lg*8 + t;
      v = W3[((size_t)agent*128 + k)*64 + col];
    }
    wbuf[tid] = f2bf(v);
  }
  if (tid < NAG * 176) {     // extended layer-1 bias: [b1 | bc1 | bs1 | 0]
    int agent = tid / 176, col = tid % 176;
    float v = 0.0f;
    if (col < 128)       v = b1[agent*128 + col];
    else if (col < 160)  v = bc1[col - 128];
    else if (col == 160) v = bs1[0];
    b1e[tid] = v;
  }
}

// ---------------- main: LDS-resident weights, agent loop, 8 waves x 16 rows ----------------
// 256 blocks (1/CU) x 512 threads. Wave w owns rows [blk*128 + w*16, +16).
// Per agent: weights live in LDS (bufA = layer1+gates 44KB, bufB = layer2+3 48KB),
// double-buffer staged with reg-staging (issue-early/write-late) hidden under compute.
// out = sum over agents accumulated in registers -> plain stores (deterministic, no atomics).
__global__ void __launch_bounds__(512, 1)
qatten_main(const float* __restrict__ states,
            const float* __restrict__ b2g, const float* __restrict__ b3g,
            const float* __restrict__ ws2p, const float* __restrict__ bs2p,
            const float* __restrict__ wc2g, const float* __restrict__ bc2p,
            const unsigned short* __restrict__ wbuf,
            const float* __restrict__ b1e,
            float* __restrict__ out)
{
  __shared__ __align__(16) unsigned short bufA[FB_L1*512];          // 44 KB
  __shared__ __align__(16) unsigned short bufB[(FB_L2+FB_L3)*512];  // 48 KB
  __shared__ __align__(16) unsigned short hlds[8 * 2048];           // 32 KB

  const int tid  = threadIdx.x;
  const int wave = tid >> 6;
  const int lane = tid & 63;
  const int lr   = lane & 15;
  const int lg   = lane >> 4;
  const int row0 = blockIdx.x * 128 + wave * 16;

  unsigned short* hp = hlds + wave * 2048;   // this wave's 4KB h region

  const float ws2  = ws2p[0];
  const float bs2v = bs2p[0];
  const float bc2v = bc2p[0];
  const float wc2a = wc2g[lr];
  const float wc2b = wc2g[16 + lr];

  const f32x4 zero4 = {0.f, 0.f, 0.f, 0.f};

  f32x4 out_acc[NJ3];
#pragma unroll
  for (int j = 0; j < NJ3; ++j) out_acc[j] = zero4;

  // ---- prologue: stage agent 0 weights ----
  {
    const u32x4* gA = (const u32x4*)wbuf;
    u32x4* lA = (u32x4*)bufA;
#pragma unroll
    for (int i = 0; i < 6; ++i) {
      int idx = tid + i*512;
      if (idx < NV_L1) lA[idx] = gA[idx];
    }
    const u32x4* gB = (const u32x4*)(wbuf + FB_L1*512);
    u32x4* lB = (u32x4*)bufB;
#pragma unroll
    for (int i = 0; i < 6; ++i)
      lB[tid + i*512] = gB[tid + i*512];
  }
  __syncthreads();

  u32x4 stg[6];   // carried stage registers (statically indexed)

  for (int a = 0; a < NAG; ++a) {
    // per-agent biases
    float b1v[NJ1], b2v[NJ2], b3v[NJ3];
#pragma unroll
    for (int j = 0; j < NJ1; ++j) b1v[j] = b1e[a*176 + j*16 + lr];
#pragma unroll
    for (int j = 0; j < NJ2; ++j) b2v[j] = b2g[a*HDIM + j*16 + lr];
#pragma unroll
    for (int j = 0; j < NJ3; ++j) b3v[j] = b3g[a*ADIM + j*16 + lr];

    // ---- A1 fragments from global states (16 rows) ----
    bf16x8 afr[4];
    {
      const float* sb = states + ((size_t)a * BATCH + row0) * DDIM;
#pragma unroll
      for (int kk = 0; kk < 4; ++kk) {
        const float* p = sb + lr*DDIM + kk*32 + lg*8;
        f32x4 v0 = *(const f32x4*)p;
        f32x4 v1 = *(const f32x4*)(p + 4);
        u32x4 w;
        w[0] = cvt_pk_bf16(v0[0], v0[1]);
        w[1] = cvt_pk_bf16(v0[2], v0[3]);
        w[2] = cvt_pk_bf16(v1[0], v1[1]);
        w[3] = cvt_pk_bf16(v1[2], v1[3]);
        afr[kk] = __builtin_bit_cast(bf16x8, w);
      }
    }

    // ---- gate & constraint tiles (j = 8,9,10) from bufA ----
    float scl[4], crow[4];
    {
      f32x4 eacc[3];
#pragma unroll
      for (int jx = 0; jx < 3; ++jx) {
        bf16x8 bfr[4];
#pragma unroll
        for (int kk = 0; kk < 4; ++kk)
          bfr[kk] = *(const bf16x8*)&bufA[((8+jx)*4 + kk)*512 + lane*8];
        f32x4 acc = zero4;
#pragma unroll
        for (int kk = 0; kk < 4; ++kk)
          acc = __builtin_amdgcn_mfma_f32_16x16x32_bf16(afr[kk], bfr[kk], acc, 0, 0, 0);
        eacc[jx] = acc;
      }
#pragma unroll
      for (int r = 0; r < 4; ++r) {
        float c0 = eacc[0][r] + b1v[8];  c0 = c0 > 0.f ? c0 : 0.f;
        float c1 = eacc[1][r] + b1v[9];  c1 = c1 > 0.f ? c1 : 0.f;
        float cd = c0*wc2a + c1*wc2b;
        cd += __shfl_xor(cd, 1);
        cd += __shfl_xor(cd, 2);
        cd += __shfl_xor(cd, 4);
        cd += __shfl_xor(cd, 8);          // sum over 16 cols within lg-group
        crow[r] = cd + bc2v;
        float sp = eacc[2][r] + b1v[10];
        sp = __shfl(sp, lane & 48);       // broadcast col-160 (lr==0) value
        sp = sp > 0.f ? sp : 0.f;
        float s = ws2 * sp + bs2v;
        scl[r] = 1.f / (1.f + __expf(-s));
      }
    }

    // ---- layer 1 main (j = 0..7) from bufA -> h (swizzled [16][128] bf16) ----
#pragma unroll
    for (int j = 0; j < 8; ++j) {
      bf16x8 bfr[4];
#pragma unroll
      for (int kk = 0; kk < 4; ++kk)
        bfr[kk] = *(const bf16x8*)&bufA[(j*4 + kk)*512 + lane*8];
      f32x4 acc = zero4;
#pragma unroll
      for (int kk = 0; kk < 4; ++kk)
        acc = __builtin_amdgcn_mfma_f32_16x16x32_bf16(afr[kk], bfr[kk], acc, 0, 0, 0);
#pragma unroll
      for (int r = 0; r < 4; ++r) {
        float hv = acc[r] + b1v[j];
        hv = hv > 0.f ? hv : 0.f;
        int row = lg*4 + r;
        int bo = row*256 + (((j*16 + lr)*2) ^ ((row & 7) << 4));   // XOR swizzle
        *(unsigned short*)((char*)hp + bo) = f2bf(hv);
      }
    }

    asm volatile("s_waitcnt lgkmcnt(0)" ::: "memory");
    // ---- A2 fragments from own h region ----
#pragma unroll
    for (int kk = 0; kk < 4; ++kk) {
      int row = lr;
      int bo = row*256 + ((kk*64 + lg*16) ^ ((row & 7) << 4));
      afr[kk] = *(const bf16x8*)((char*)hp + bo);
    }

    // ---- write carried L23(a) stage into bufB (bufB free since B2 of prev iter) ----
    if (a > 0) {
      u32x4* lB = (u32x4*)bufB;
#pragma unroll
      for (int i = 0; i < 6; ++i)
        lB[tid + i*512] = stg[i];
    }
    __syncthreads();   // B1: bufA free for restage; bufB (L23(a)) published

    // ---- issue loads: L1(a+1) -> stg (hidden under L2+L3 compute) ----
    if (a < NAG-1) {
      const u32x4* g = (const u32x4*)(wbuf + (size_t)(a+1)*WAGENT);
#pragma unroll
      for (int i = 0; i < 6; ++i) {
        int idx = tid + i*512;
        if (idx < NV_L1) stg[i] = g[idx];
      }
    }

    // ---- layer 2 (j = 0..7) from bufB -> h ----
#pragma unroll
    for (int j = 0; j < 8; ++j) {
      bf16x8 bfr[4];
#pragma unroll
      for (int kk = 0; kk < 4; ++kk)
        bfr[kk] = *(const bf16x8*)&bufB[(j*4 + kk)*512 + lane*8];
      f32x4 acc = zero4;
#pragma unroll
      for (int kk = 0; kk < 4; ++kk)
        acc = __builtin_amdgcn_mfma_f32_16x16x32_bf16(afr[kk], bfr[kk], acc, 0, 0, 0);
#pragma unroll
      for (int r = 0; r < 4; ++r) {
        float hv = acc[r] + b2v[j];
        hv = hv > 0.f ? hv : 0.f;
        int row = lg*4 + r;
        int bo = row*256 + (((j*16 + lr)*2) ^ ((row & 7) << 4));
        *(unsigned short*)((char*)hp + bo) = f2bf(hv);   // overwrite h1
      }
    }

    asm volatile("s_waitcnt lgkmcnt(0)" ::: "memory");
    // ---- A3 fragments from h2 ----
#pragma unroll
    for (int kk = 0; kk < 4; ++kk) {
      int row = lr;
      int bo = row*256 + ((kk*64 + lg*16) ^ ((row & 7) << 4));
      afr[kk] = *(const bf16x8*)((char*)hp + bo);
    }

    // ---- layer 3 (j = 0..3) from bufB: gated accumulate into out_acc ----
#pragma unroll
    for (int j = 0; j < NJ3; ++j) {
      bf16x8 bfr[4];
#pragma unroll
      for (int kk = 0; kk < 4; ++kk)
        bfr[kk] = *(const bf16x8*)&bufB[(FB_L2 + j*4 + kk)*512 + lane*8];
      f32x4 acc = zero4;
#pragma unroll
      for (int kk = 0; kk < 4; ++kk)
        acc = __builtin_amdgcn_mfma_f32_16x16x32_bf16(afr[kk], bfr[kk], acc, 0, 0, 0);
#pragma unroll
      for (int r = 0; r < 4; ++r)
        out_acc[j][r] += scl[r] * (acc[r] + b3v[j]) + crow[r];
    }

    // ---- write carried L1(a+1) stage into bufA (free since B1) ----
    if (a < NAG-1) {
      u32x4* lA = (u32x4*)bufA;
#pragma unroll
      for (int i = 0; i < 6; ++i) {
        int idx = tid + i*512;
        if (idx < NV_L1) lA[idx] = stg[i];
      }
    }
    __syncthreads();   // B2: bufA (L1(a+1)) published; bufB free for restage

    // ---- issue loads: L23(a+1) -> stg (hidden under next A1+gates+L1 compute) ----
    if (a < NAG-1) {
      const u32x4* g = (const u32x4*)(wbuf + (size_t)(a+1)*WAGENT + FB_L1*512);
#pragma unroll
      for (int i = 0; i < 6; ++i)
        stg[i] = g[tid + i*512];
    }
  }

  // ---- final store: out = mean over agents (deterministic, no atomics) ----
#pragma unroll
  for (int j = 0; j < NJ3; ++j)
#pragma unroll
    for (int r = 0; r < 4; ++r) {
      size_t row = (size_t)row0 + lg*4 + r;
      out[row*ADIM + j*16 + lr] = out_acc[j][r] * 0.125f;
    }
}

extern "C" void kernel_launch(void* const* d_in, const int* in_sizes, int n_in,
                              void* d_out, int out_size, void* d_ws, size_t ws_size,
                              hipStream_t stream)
{
  const float* states = (const float*)d_in[0];
  const float* W1  = (const float*)d_in[1];
  const float* b1  = (const float*)d_in[2];
  const float* W2  = (const float*)d_in[3];
  const float* b2  = (const float*)d_in[4];
  const float* W3  = (const float*)d_in[5];
  const float* b3  = (const float*)d_in[6];
  const float* Ws1 = (const float*)d_in[13];
  const float* bs1 = (const float*)d_in[14];
  const float* Ws2 = (const float*)d_in[15];
  const float* bs2 = (const float*)d_in[16];
  const float* Wc1 = (const float*)d_in[17];
  const float* bc1 = (const float*)d_in[18];
  const float* Wc2 = (const float*)d_in[19];
  const float* bc2 = (const float*)d_in[20];

  unsigned short* wbuf = (unsigned short*)d_ws;
  float* b1e = (float*)((char*)d_ws + (size_t)NAG * WAGENT * 2);

  dim3 pb(256), pg((NAG * WAGENT + 255) / 256);
  prep_weights<<<pg, pb, 0, stream>>>(W1, W2, W3, Wc1, Ws1, b1, bc1, bs1, wbuf, b1e);

  dim3 mb(512), mg(BATCH / 128);   // 256 blocks = 1 per CU, 8 waves each
  qatten_main<<<mg, mb, 0, stream>>>(states, b2, b3, Ws2, bs2, Wc2, bc2,
                                     wbuf, b1e, (float*)d_out);
}

// Round 8
// 65.363 us; speedup vs baseline: 1.3658x; 1.0286x over previous
//
#include <hip/hip_runtime.h>
#include <hip/hip_bf16.h>

#define NAG 8
#define BATCH 32768
#define DDIM 128
#define ADIM 64
#define HDIM 128

#define NJ1 11            // layer1 col tiles: 128 (W1) + 32 (Wc1) + 1 (Ws1) -> 176 cols
#define NJ2 8
#define NJ3 4
#define FB_L1 (NJ1*4)     // 44 frag blocks (44KB)
#define FB_L2 (NJ2*4)     // 32
#define FB_L3 (NJ3*4)     // 16
#define FB_B  (FB_L2+FB_L3)         // 48 frag blocks in bufB
#define FB_TOT (FB_L1+FB_L2+FB_L3)  // 92
#define WAGENT (FB_TOT*512)         // 47104 ushort per agent (92KB)

typedef __attribute__((ext_vector_type(8))) short bf16x8;
typedef __attribute__((ext_vector_type(4))) float f32x4;
typedef __attribute__((ext_vector_type(4))) unsigned int u32x4;

static __device__ __forceinline__ unsigned short f2bf(float f) {
  unsigned int u = __builtin_bit_cast(unsigned int, f);
  u += 0x7fffu + ((u >> 16) & 1u);          // RNE (inputs are finite)
  return (unsigned short)(u >> 16);
}

static __device__ __forceinline__ unsigned int cvt_pk_bf16(float a, float b) {
  unsigned int r;
  asm("v_cvt_pk_bf16_f32 %0, %1, %2" : "=v"(r) : "v"(a), "v"(b));
  return r;
}

// async global->LDS, 16B per lane; LDS dest = uniform base + lane*16 (linear)
static __device__ __forceinline__ void gload_lds16(const void* g, void* l) {
  __builtin_amdgcn_global_load_lds(
      (const __attribute__((address_space(1))) unsigned int*)g,
      (__attribute__((address_space(3))) unsigned int*)l, 16, 0, 0);
}

// ---------------- prep: f32 weights -> bf16 B-fragment-linear layout (proven) ----------------
// frag block fb=(j,kk): 512 bf16; element l*8+t = W[k = kk*32 + (l>>4)*8 + t][col = j*16 + (l&15)]
__global__ void __launch_bounds__(256)
prep_weights(const float* __restrict__ W1, const float* __restrict__ W2,
             const float* __restrict__ W3, const float* __restrict__ Wc1,
             const float* __restrict__ Ws1, const float* __restrict__ b1,
             const float* __restrict__ bc1, const float* __restrict__ bs1,
             unsigned short* __restrict__ wbuf, float* __restrict__ b1e)
{
  int tid = blockIdx.x * 256 + threadIdx.x;
  if (tid < NAG * WAGENT) {
    int agent = tid / WAGENT;
    int rem   = tid % WAGENT;
    int fb = rem >> 9;
    int li = rem & 511;
    int l = li >> 3, t = li & 7;
    int lr = l & 15, lg = l >> 4;
    float v = 0.0f;
    if (fb < FB_L1) {
      int j = fb >> 2, kk = fb & 3;
      int col = j*16 + lr, k = kk*32 + lg*8 + t;
      if (col < 128)       v = W1[((size_t)agent*128 + k)*128 + col];
      else if (col < 160)  v = Wc1[k*32 + (col-128)];
      else if (col == 160) v = Ws1[k];
    } else if (fb < FB_L1 + FB_L2) {
      int f = fb - FB_L1;
      int j = f >> 2, kk = f & 3;
      int col = j*16 + lr, k = kk*32 + lg*8 + t;
      v = W2[((size_t)agent*128 + k)*128 + col];
    } else {
      int f = fb - FB_L1 - FB_L2;
      int j = f >> 2, kk = f & 3;
      int col = j*16 + lr, k = kk*32 + lg*8 + t;
      v = W3[((size_t)agent*128 + k)*64 + col];
    }
    wbuf[tid] = f2bf(v);
  }
  if (tid < NAG * 176) {     // extended layer-1 bias: [b1 | bc1 | bs1 | 0]
    int agent = tid / 176, col = tid % 176;
    float v = 0.0f;
    if (col < 128)       v = b1[agent*128 + col];
    else if (col < 160)  v = bc1[col - 128];
    else if (col == 160) v = bs1[0];
    b1e[tid] = v;
  }
}

// ---------------- main: LDS weights via global_load_lds dbuf; 2-deep ds_read pipeline ----------
// 256 blocks (1/CU) x 512 threads (8 waves). Wave w owns rows [blk*128 + w*16, +16).
// Per agent: bufA (gates+L1, 44KB) / bufB (L2+L3, 48KB) staged by global_load_lds;
// each buffer's loads are issued right after the barrier that retires its last reader
// and published by the NEXT barrier's vmcnt(0) drain — loads fly under a full compute phase.
// No asm fences: h is per-wave and DS ops are in-order per wave.
// out = 8-agent sum accumulated in registers -> plain deterministic stores.
__global__ void __launch_bounds__(512, 1)
qatten_main(const float* __restrict__ states,
            const float* __restrict__ b2g, const float* __restrict__ b3g,
            const float* __restrict__ ws2p, const float* __restrict__ bs2p,
            const float* __restrict__ wc2g, const float* __restrict__ bc2p,
            const unsigned short* __restrict__ wbuf,
            const float* __restrict__ b1e,
            float* __restrict__ out)
{
  __shared__ __align__(16) unsigned short bufA[FB_L1*512];   // 44 KB
  __shared__ __align__(16) unsigned short bufB[FB_B*512];    // 48 KB
  __shared__ __align__(16) unsigned short hlds[8 * 2048];    // 32 KB

  const int tid  = threadIdx.x;
  const int wave = tid >> 6;
  const int lane = tid & 63;
  const int lr   = lane & 15;
  const int lg   = lane >> 4;
  const int row0 = blockIdx.x * 128 + wave * 16;

  unsigned short* hp = hlds + wave * 2048;   // this wave's 4KB h region

  const float ws2  = ws2p[0];
  const float bs2v = bs2p[0];
  const float bc2v = bc2p[0];
  const float wc2a = wc2g[lr];
  const float wc2b = wc2g[16 + lr];

  const f32x4 zero4 = {0.f, 0.f, 0.f, 0.f};

  f32x4 out_acc[NJ3];
#pragma unroll
  for (int j = 0; j < NJ3; ++j) out_acc[j] = zero4;

  // ---- prologue: stage agent 0 (bufA + bufB) ----
  {
    const char* sA = (const char*)wbuf;
    for (int c = wave; c < FB_L1; c += 8)
      gload_lds16(sA + c*1024 + lane*16, (char*)bufA + c*1024);
    const char* sB = (const char*)(wbuf + FB_L1*512);
    for (int c = wave; c < FB_B; c += 8)
      gload_lds16(sB + c*1024 + lane*16, (char*)bufB + c*1024);
  }
  __syncthreads();                    // vmcnt(0): agent-0 weights published

  for (int a = 0; a < NAG; ++a) {
    // per-agent biases
    float b1v[NJ1], b2v[NJ2], b3v[NJ3];
#pragma unroll
    for (int j = 0; j < NJ1; ++j) b1v[j] = b1e[a*176 + j*16 + lr];
#pragma unroll
    for (int j = 0; j < NJ2; ++j) b2v[j] = b2g[a*HDIM + j*16 + lr];
#pragma unroll
    for (int j = 0; j < NJ3; ++j) b3v[j] = b3g[a*ADIM + j*16 + lr];

    // ---- A1 fragments from global states (16 rows) ----
    bf16x8 afr[4];
    {
      const float* sb = states + ((size_t)a * BATCH + row0) * DDIM;
#pragma unroll
      for (int kk = 0; kk < 4; ++kk) {
        const float* p = sb + lr*DDIM + kk*32 + lg*8;
        f32x4 v0 = *(const f32x4*)p;
        f32x4 v1 = *(const f32x4*)(p + 4);
        u32x4 w;
        w[0] = cvt_pk_bf16(v0[0], v0[1]);
        w[1] = cvt_pk_bf16(v0[2], v0[3]);
        w[2] = cvt_pk_bf16(v1[0], v1[1]);
        w[3] = cvt_pk_bf16(v1[2], v1[3]);
        afr[kk] = __builtin_bit_cast(bf16x8, w);
      }
    }

    // ---- phase 1: L1 (j=0..7) + gates (j=8..10) from bufA, 2-deep pipelined ----
    f32x4 eacc[3];
    {
      bf16x8 pf[2][4];
#pragma unroll
      for (int kk = 0; kk < 4; ++kk)
        pf[0][kk] = *(const bf16x8*)&bufA[kk*512 + lane*8];
#pragma unroll
      for (int j = 0; j < 11; ++j) {
        if (j < 10) {
#pragma unroll
          for (int kk = 0; kk < 4; ++kk)
            pf[(j+1)&1][kk] = *(const bf16x8*)&bufA[((j+1)*4 + kk)*512 + lane*8];
        }
        f32x4 acc = zero4;
#pragma unroll
        for (int kk = 0; kk < 4; ++kk)
          acc = __builtin_amdgcn_mfma_f32_16x16x32_bf16(afr[kk], pf[j&1][kk], acc, 0, 0, 0);
        if (j < 8) {
#pragma unroll
          for (int r = 0; r < 4; ++r) {
            float hv = acc[r] + b1v[j];
            hv = hv > 0.f ? hv : 0.f;
            int row = lg*4 + r;
            int bo = row*256 + (((j*16 + lr)*2) ^ ((row & 7) << 4));   // XOR swizzle
            *(unsigned short*)((char*)hp + bo) = f2bf(hv);
          }
        } else {
          eacc[j-8] = acc;
        }
      }
    }

    // ---- gate & constraint scalars ----
    float scl[4], crow[4];
#pragma unroll
    for (int r = 0; r < 4; ++r) {
      float c0 = eacc[0][r] + b1v[8];  c0 = c0 > 0.f ? c0 : 0.f;
      float c1 = eacc[1][r] + b1v[9];  c1 = c1 > 0.f ? c1 : 0.f;
      float cd = c0*wc2a + c1*wc2b;
      cd += __shfl_xor(cd, 1);
      cd += __shfl_xor(cd, 2);
      cd += __shfl_xor(cd, 4);
      cd += __shfl_xor(cd, 8);          // sum over 16 cols within lg-group
      crow[r] = cd + bc2v;
      float sp = eacc[2][r] + b1v[10];
      sp = __shfl(sp, lane & 48);       // broadcast col-160 (lr==0) value
      sp = sp > 0.f ? sp : 0.f;
      float s = ws2 * sp + bs2v;
      scl[r] = 1.f / (1.f + __expf(-s));
    }

    __syncthreads();   // B1: all waves done reading bufA(a); bufB(a) published (vmcnt 0)

    // issue bufA <- L1(a+1): in flight under phases 2+3
    if (a < NAG-1) {
      const char* sA = (const char*)(wbuf + (size_t)(a+1)*WAGENT);
      for (int c = wave; c < FB_L1; c += 8)
        gload_lds16(sA + c*1024 + lane*16, (char*)bufA + c*1024);
    }

    // ---- A2 fragments from own h region ----
#pragma unroll
    for (int kk = 0; kk < 4; ++kk) {
      int row = lr;
      int bo = row*256 + ((kk*64 + lg*16) ^ ((row & 7) << 4));
      afr[kk] = *(const bf16x8*)((char*)hp + bo);
    }

    // ---- phase 2: L2 (j=0..7) from bufB, 2-deep pipelined ----
    {
      bf16x8 pf[2][4];
#pragma unroll
      for (int kk = 0; kk < 4; ++kk)
        pf[0][kk] = *(const bf16x8*)&bufB[kk*512 + lane*8];
#pragma unroll
      for (int j = 0; j < 8; ++j) {
        if (j < 7) {
#pragma unroll
          for (int kk = 0; kk < 4; ++kk)
            pf[(j+1)&1][kk] = *(const bf16x8*)&bufB[((j+1)*4 + kk)*512 + lane*8];
        }
        f32x4 acc = zero4;
#pragma unroll
        for (int kk = 0; kk < 4; ++kk)
          acc = __builtin_amdgcn_mfma_f32_16x16x32_bf16(afr[kk], pf[j&1][kk], acc, 0, 0, 0);
#pragma unroll
        for (int r = 0; r < 4; ++r) {
          float hv = acc[r] + b2v[j];
          hv = hv > 0.f ? hv : 0.f;
          int row = lg*4 + r;
          int bo = row*256 + (((j*16 + lr)*2) ^ ((row & 7) << 4));
          *(unsigned short*)((char*)hp + bo) = f2bf(hv);   // overwrite h1 (A2 in regs)
        }
      }
    }

    // ---- A3 fragments from h2 ----
#pragma unroll
    for (int kk = 0; kk < 4; ++kk) {
      int row = lr;
      int bo = row*256 + ((kk*64 + lg*16) ^ ((row & 7) << 4));
      afr[kk] = *(const bf16x8*)((char*)hp + bo);
    }

    // ---- phase 3: L3 (j=0..3) from bufB, pipelined; gated accumulate ----
    {
      bf16x8 pf[2][4];
#pragma unroll
      for (int kk = 0; kk < 4; ++kk)
        pf[0][kk] = *(const bf16x8*)&bufB[(FB_L2 + kk)*512 + lane*8];
#pragma unroll
      for (int j = 0; j < NJ3; ++j) {
        if (j < NJ3-1) {
#pragma unroll
          for (int kk = 0; kk < 4; ++kk)
            pf[(j+1)&1][kk] = *(const bf16x8*)&bufB[(FB_L2 + (j+1)*4 + kk)*512 + lane*8];
        }
        f32x4 acc = zero4;
#pragma unroll
        for (int kk = 0; kk < 4; ++kk)
          acc = __builtin_amdgcn_mfma_f32_16x16x32_bf16(afr[kk], pf[j&1][kk], acc, 0, 0, 0);
#pragma unroll
        for (int r = 0; r < 4; ++r)
          out_acc[j][r] += scl[r] * (acc[r] + b3v[j]) + crow[r];
      }
    }

    __syncthreads();   // B2: all waves done reading bufB(a); bufA(a+1) published (vmcnt 0)

    // issue bufB <- L23(a+1): in flight under next agent's A1 + phase 1
    if (a < NAG-1) {
      const char* sB = (const char*)(wbuf + (size_t)(a+1)*WAGENT + FB_L1*512);
      for (int c = wave; c < FB_B; c += 8)
        gload_lds16(sB + c*1024 + lane*16, (char*)bufB + c*1024);
    }
  }

  // ---- final store: out = mean over agents (deterministic, no atomics) ----
#pragma unroll
  for (int j = 0; j < NJ3; ++j)
#pragma unroll
    for (int r = 0; r < 4; ++r) {
      size_t row = (size_t)row0 + lg*4 + r;
      out[row*ADIM + j*16 + lr] = out_acc[j][r] * 0.125f;
    }
}

extern "C" void kernel_launch(void* const* d_in, const int* in_sizes, int n_in,
                              void* d_out, int out_size, void* d_ws, size_t ws_size,
                              hipStream_t stream)
{
  const float* states = (const float*)d_in[0];
  const float* W1  = (const float*)d_in[1];
  const float* b1  = (const float*)d_in[2];
  const float* W2  = (const float*)d_in[3];
  const float* b2  = (const float*)d_in[4];
  const float* W3  = (const float*)d_in[5];
  const float* b3  = (const float*)d_in[6];
  const float* Ws1 = (const float*)d_in[13];
  const float* bs1 = (const float*)d_in[14];
  const float* Ws2 = (const float*)d_in[15];
  const float* bs2 = (const float*)d_in[16];
  const float* Wc1 = (const float*)d_in[17];
  const float* bc1 = (const float*)d_in[18];
  const float* Wc2 = (const float*)d_in[19];
  const float* bc2 = (const float*)d_in[20];

  unsigned short* wbuf = (unsigned short*)d_ws;
  float* b1e = (float*)((char*)d_ws + (size_t)NAG * WAGENT * 2);

  dim3 pb(256), pg((NAG * WAGENT + 255) / 256);
  prep_weights<<<pg, pb, 0, stream>>>(W1, W2, W3, Wc1, Ws1, b1, bc1, bs1, wbuf, b1e);

  dim3 mb(512), mg(BATCH / 128);   // 256 blocks = 1 per CU, 8 waves each
  qatten_main<<<mg, mb, 0, stream>>>(states, b2, b3, Ws2, bs2, Wc2, bc2,
                                     wbuf, b1e, (float*)d_out);
}

// Round 9
// 62.928 us; speedup vs baseline: 1.4187x; 1.0387x over previous
//
#include <hip/hip_runtime.h>
#include <hip/hip_bf16.h>

#define NAG 8
#define BATCH 32768
#define DDIM 128
#define ADIM 64
#define HDIM 128

#define NJ1 11            // layer1 col tiles: 128 (W1) + 32 (Wc1) + 1 (Ws1) -> 176 cols
#define NJ2 8
#define NJ3 4
#define FB_L1 (NJ1*4)     // 44 frag blocks (44KB)
#define FB_L2 (NJ2*4)     // 32
#define FB_L3 (NJ3*4)     // 16
#define FB_B  (FB_L2+FB_L3)         // 48 frag blocks in bufB
#define FB_TOT (FB_L1+FB_L2+FB_L3)  // 92
#define WAGENT (FB_TOT*512)         // 47104 ushort per agent (92KB)

typedef __attribute__((ext_vector_type(8))) short bf16x8;
typedef __attribute__((ext_vector_type(4))) float f32x4;
typedef __attribute__((ext_vector_type(4))) unsigned int u32x4;

static __device__ __forceinline__ unsigned short f2bf(float f) {
  unsigned int u = __builtin_bit_cast(unsigned int, f);
  u += 0x7fffu + ((u >> 16) & 1u);          // RNE (inputs are finite)
  return (unsigned short)(u >> 16);
}

static __device__ __forceinline__ unsigned int cvt_pk_bf16(float a, float b) {
  unsigned int r;
  asm("v_cvt_pk_bf16_f32 %0, %1, %2" : "=v"(r) : "v"(a), "v"(b));
  return r;
}

// async global->LDS, 16B per lane; LDS dest = uniform base + lane*16 (linear)
static __device__ __forceinline__ void gload_lds16(const void* g, void* l) {
  __builtin_amdgcn_global_load_lds(
      (const __attribute__((address_space(1))) unsigned int*)g,
      (__attribute__((address_space(3))) unsigned int*)l, 16, 0, 0);
}

// ---------------- prep: f32 weights -> bf16 B-fragment-linear layout (proven) ----------------
// frag block fb=(j,kk): 512 bf16; element l*8+t = W[k = kk*32 + (l>>4)*8 + t][col = j*16 + (l&15)]
__global__ void __launch_bounds__(256)
prep_weights(const float* __restrict__ W1, const float* __restrict__ W2,
             const float* __restrict__ W3, const float* __restrict__ Wc1,
             const float* __restrict__ Ws1, const float* __restrict__ b1,
             const float* __restrict__ bc1, const float* __restrict__ bs1,
             unsigned short* __restrict__ wbuf, float* __restrict__ b1e)
{
  int tid = blockIdx.x * 256 + threadIdx.x;
  if (tid < NAG * WAGENT) {
    int agent = tid / WAGENT;
    int rem   = tid % WAGENT;
    int fb = rem >> 9;
    int li = rem & 511;
    int l = li >> 3, t = li & 7;
    int lr = l & 15, lg = l >> 4;
    float v = 0.0f;
    if (fb < FB_L1) {
      int j = fb >> 2, kk = fb & 3;
      int col = j*16 + lr, k = kk*32 + lg*8 + t;
      if (col < 128)       v = W1[((size_t)agent*128 + k)*128 + col];
      else if (col < 160)  v = Wc1[k*32 + (col-128)];
      else if (col == 160) v = Ws1[k];
    } else if (fb < FB_L1 + FB_L2) {
      int f = fb - FB_L1;
      int j = f >> 2, kk = f & 3;
      int col = j*16 + lr, k = kk*32 + lg*8 + t;
      v = W2[((size_t)agent*128 + k)*128 + col];
    } else {
      int f = fb - FB_L1 - FB_L2;
      int j = f >> 2, kk = f & 3;
      int col = j*16 + lr, k = kk*32 + lg*8 + t;
      v = W3[((size_t)agent*128 + k)*64 + col];
    }
    wbuf[tid] = f2bf(v);
  }
  if (tid < NAG * 176) {     // extended layer-1 bias: [b1 | bc1 | bs1 | 0]
    int agent = tid / 176, col = tid % 176;
    float v = 0.0f;
    if (col < 128)       v = b1[agent*128 + col];
    else if (col < 160)  v = bc1[col - 128];
    else if (col == 160) v = bs1[0];
    b1e[tid] = v;
  }
}

// ---------------- main: LDS weights dbuf + cross-agent A1/bias prefetch + 3-deep DS pipeline ----
// 256 blocks (1/CU) x 512 threads (8 waves). Wave w owns rows [blk*128 + w*16, +16).
// Cross-agent prefetch: states (sreg) and biases (b*n) for agent a+1 are loaded while
// agent a computes -> agent-start has ZERO exposed global latency.
// A2 fragment reads hoisted before barrier B1 (own-wave DS in-order).
__global__ void __launch_bounds__(512, 1)
qatten_main(const float* __restrict__ states,
            const float* __restrict__ b2g, const float* __restrict__ b3g,
            const float* __restrict__ ws2p, const float* __restrict__ bs2p,
            const float* __restrict__ wc2g, const float* __restrict__ bc2p,
            const unsigned short* __restrict__ wbuf,
            const float* __restrict__ b1e,
            float* __restrict__ out)
{
  __shared__ __align__(16) unsigned short bufA[FB_L1*512];   // 44 KB
  __shared__ __align__(16) unsigned short bufB[FB_B*512];    // 48 KB
  __shared__ __align__(16) unsigned short hlds[8 * 2048];    // 32 KB

  const int tid  = threadIdx.x;
  const int wave = tid >> 6;
  const int lane = tid & 63;
  const int lr   = lane & 15;
  const int lg   = lane >> 4;
  const int row0 = blockIdx.x * 128 + wave * 16;

  unsigned short* hp = hlds + wave * 2048;   // this wave's 4KB h region

  const float ws2  = ws2p[0];
  const float bs2v = bs2p[0];
  const float bc2v = bc2p[0];
  const float wc2a = wc2g[lr];
  const float wc2b = wc2g[16 + lr];

  const f32x4 zero4 = {0.f, 0.f, 0.f, 0.f};

  f32x4 out_acc[NJ3];
#pragma unroll
  for (int j = 0; j < NJ3; ++j) out_acc[j] = zero4;

  // ---- prologue: stage agent-0 weights; prefetch agent-0 states & biases ----
  {
    const char* sA = (const char*)wbuf;
    for (int c = wave; c < FB_L1; c += 8)
      gload_lds16(sA + c*1024 + lane*16, (char*)bufA + c*1024);
    const char* sB = (const char*)(wbuf + FB_L1*512);
    for (int c = wave; c < FB_B; c += 8)
      gload_lds16(sB + c*1024 + lane*16, (char*)bufB + c*1024);
  }

  f32x4 sreg[8];            // raw states for the NEXT agent (2 per kk)
  float b1n[NJ1], b2n[NJ2], b3n[NJ3];
  {
    const float* sb = states + (size_t)row0 * DDIM;     // agent 0
#pragma unroll
    for (int kk = 0; kk < 4; ++kk) {
      const float* p = sb + lr*DDIM + kk*32 + lg*8;
      sreg[kk*2]   = *(const f32x4*)p;
      sreg[kk*2+1] = *(const f32x4*)(p + 4);
    }
#pragma unroll
    for (int j = 0; j < NJ1; ++j) b1n[j] = b1e[j*16 + lr];
#pragma unroll
    for (int j = 0; j < NJ2; ++j) b2n[j] = b2g[j*16 + lr];
#pragma unroll
    for (int j = 0; j < NJ3; ++j) b3n[j] = b3g[j*16 + lr];
  }
  __syncthreads();                    // vmcnt(0): agent-0 weights published

  for (int a = 0; a < NAG; ++a) {
    // ---- consume prefetched biases ----
    float b1v[NJ1], b2v[NJ2], b3v[NJ3];
#pragma unroll
    for (int j = 0; j < NJ1; ++j) b1v[j] = b1n[j];
#pragma unroll
    for (int j = 0; j < NJ2; ++j) b2v[j] = b2n[j];
#pragma unroll
    for (int j = 0; j < NJ3; ++j) b3v[j] = b3n[j];

    // ---- convert prefetched states -> A1 fragments (pure VALU, no memory wait) ----
    bf16x8 afr[4];
#pragma unroll
    for (int kk = 0; kk < 4; ++kk) {
      f32x4 v0 = sreg[kk*2], v1 = sreg[kk*2+1];
      u32x4 w;
      w[0] = cvt_pk_bf16(v0[0], v0[1]);
      w[1] = cvt_pk_bf16(v0[2], v0[3]);
      w[2] = cvt_pk_bf16(v1[0], v1[1]);
      w[3] = cvt_pk_bf16(v1[2], v1[3]);
      afr[kk] = __builtin_bit_cast(bf16x8, w);
    }

    // ---- issue next agent's states + bias loads (land under phases 1-3) ----
    if (a < NAG-1) {
      const float* sb = states + ((size_t)(a+1) * BATCH + row0) * DDIM;
#pragma unroll
      for (int kk = 0; kk < 4; ++kk) {
        const float* p = sb + lr*DDIM + kk*32 + lg*8;
        sreg[kk*2]   = *(const f32x4*)p;
        sreg[kk*2+1] = *(const f32x4*)(p + 4);
      }
#pragma unroll
      for (int j = 0; j < NJ1; ++j) b1n[j] = b1e[(a+1)*176 + j*16 + lr];
#pragma unroll
      for (int j = 0; j < NJ2; ++j) b2n[j] = b2g[(a+1)*HDIM + j*16 + lr];
#pragma unroll
      for (int j = 0; j < NJ3; ++j) b3n[j] = b3g[(a+1)*ADIM + j*16 + lr];
    }

    // ---- phase 1: L1 (j=0..7) + gates (j=8..10) from bufA, 3-deep pipelined ----
    f32x4 eacc[3];
    {
      bf16x8 pf[3][4];
#pragma unroll
      for (int kk = 0; kk < 4; ++kk) {
        pf[0][kk] = *(const bf16x8*)&bufA[(0*4 + kk)*512 + lane*8];
        pf[1][kk] = *(const bf16x8*)&bufA[(1*4 + kk)*512 + lane*8];
      }
#pragma unroll
      for (int j = 0; j < 11; ++j) {
        if (j + 2 <= 10) {
#pragma unroll
          for (int kk = 0; kk < 4; ++kk)
            pf[(j+2)%3][kk] = *(const bf16x8*)&bufA[((j+2)*4 + kk)*512 + lane*8];
        }
        f32x4 acc = zero4;
#pragma unroll
        for (int kk = 0; kk < 4; ++kk)
          acc = __builtin_amdgcn_mfma_f32_16x16x32_bf16(afr[kk], pf[j%3][kk], acc, 0, 0, 0);
        if (j < 8) {
#pragma unroll
          for (int r = 0; r < 4; ++r) {
            float hv = acc[r] + b1v[j];
            hv = hv > 0.f ? hv : 0.f;
            int row = lg*4 + r;
            int bo = row*256 + (((j*16 + lr)*2) ^ ((row & 7) << 4));   // XOR swizzle
            *(unsigned short*)((char*)hp + bo) = f2bf(hv);
          }
        } else {
          eacc[j-8] = acc;
        }
      }
    }

    // ---- gate & constraint scalars ----
    float scl[4], crow[4];
#pragma unroll
    for (int r = 0; r < 4; ++r) {
      float c0 = eacc[0][r] + b1v[8];  c0 = c0 > 0.f ? c0 : 0.f;
      float c1 = eacc[1][r] + b1v[9];  c1 = c1 > 0.f ? c1 : 0.f;
      float cd = c0*wc2a + c1*wc2b;
      cd += __shfl_xor(cd, 1);
      cd += __shfl_xor(cd, 2);
      cd += __shfl_xor(cd, 4);
      cd += __shfl_xor(cd, 8);          // sum over 16 cols within lg-group
      crow[r] = cd + bc2v;
      float sp = eacc[2][r] + b1v[10];
      sp = __shfl(sp, lane & 48);       // broadcast col-160 (lr==0) value
      sp = sp > 0.f ? sp : 0.f;
      float s = ws2 * sp + bs2v;
      scl[r] = 1.f / (1.f + __expf(-s));
    }

    // ---- A2 fragments from own h region (hoisted BEFORE barrier: own-wave DS in-order) ----
#pragma unroll
    for (int kk = 0; kk < 4; ++kk) {
      int row = lr;
      int bo = row*256 + ((kk*64 + lg*16) ^ ((row & 7) << 4));
      afr[kk] = *(const bf16x8*)((char*)hp + bo);
    }

    __syncthreads();   // B1: all waves done reading bufA(a); bufB(a) published (vmcnt 0)

    // issue bufA <- L1(a+1): in flight under phases 2+3
    if (a < NAG-1) {
      const char* sA = (const char*)(wbuf + (size_t)(a+1)*WAGENT);
      for (int c = wave; c < FB_L1; c += 8)
        gload_lds16(sA + c*1024 + lane*16, (char*)bufA + c*1024);
    }

    // ---- phase 2: L2 (j=0..7) from bufB, 3-deep pipelined ----
    {
      bf16x8 pf[3][4];
#pragma unroll
      for (int kk = 0; kk < 4; ++kk) {
        pf[0][kk] = *(const bf16x8*)&bufB[(0*4 + kk)*512 + lane*8];
        pf[1][kk] = *(const bf16x8*)&bufB[(1*4 + kk)*512 + lane*8];
      }
#pragma unroll
      for (int j = 0; j < 8; ++j) {
        if (j + 2 <= 7) {
#pragma unroll
          for (int kk = 0; kk < 4; ++kk)
            pf[(j+2)%3][kk] = *(const bf16x8*)&bufB[((j+2)*4 + kk)*512 + lane*8];
        }
        f32x4 acc = zero4;
#pragma unroll
        for (int kk = 0; kk < 4; ++kk)
          acc = __builtin_amdgcn_mfma_f32_16x16x32_bf16(afr[kk], pf[j%3][kk], acc, 0, 0, 0);
#pragma unroll
        for (int r = 0; r < 4; ++r) {
          float hv = acc[r] + b2v[j];
          hv = hv > 0.f ? hv : 0.f;
          int row = lg*4 + r;
          int bo = row*256 + (((j*16 + lr)*2) ^ ((row & 7) << 4));
          *(unsigned short*)((char*)hp + bo) = f2bf(hv);   // overwrite h1 (A2 in regs)
        }
      }
    }

    // ---- A3 fragments from h2 (own-wave DS in-order) ----
#pragma unroll
    for (int kk = 0; kk < 4; ++kk) {
      int row = lr;
      int bo = row*256 + ((kk*64 + lg*16) ^ ((row & 7) << 4));
      afr[kk] = *(const bf16x8*)((char*)hp + bo);
    }

    // ---- phase 3: L3 (j=0..3) from bufB, 2-deep; gated accumulate ----
    {
      bf16x8 pf[2][4];
#pragma unroll
      for (int kk = 0; kk < 4; ++kk)
        pf[0][kk] = *(const bf16x8*)&bufB[(FB_L2 + kk)*512 + lane*8];
#pragma unroll
      for (int j = 0; j < NJ3; ++j) {
        if (j < NJ3-1) {
#pragma unroll
          for (int kk = 0; kk < 4; ++kk)
            pf[(j+1)&1][kk] = *(const bf16x8*)&bufB[(FB_L2 + (j+1)*4 + kk)*512 + lane*8];
        }
        f32x4 acc = zero4;
#pragma unroll
        for (int kk = 0; kk < 4; ++kk)
          acc = __builtin_amdgcn_mfma_f32_16x16x32_bf16(afr[kk], pf[j&1][kk], acc, 0, 0, 0);
#pragma unroll
        for (int r = 0; r < 4; ++r)
          out_acc[j][r] += scl[r] * (acc[r] + b3v[j]) + crow[r];
      }
    }

    __syncthreads();   // B2: all waves done reading bufB(a); bufA(a+1) published (vmcnt 0)

    // issue bufB <- L23(a+1): in flight under next agent's phase 1
    if (a < NAG-1) {
      const char* sB = (const char*)(wbuf + (size_t)(a+1)*WAGENT + FB_L1*512);
      for (int c = wave; c < FB_B; c += 8)
        gload_lds16(sB + c*1024 + lane*16, (char*)bufB + c*1024);
    }
  }

  // ---- final store: out = mean over agents (deterministic, no atomics) ----
#pragma unroll
  for (int j = 0; j < NJ3; ++j)
#pragma unroll
    for (int r = 0; r < 4; ++r) {
      size_t row = (size_t)row0 + lg*4 + r;
      out[row*ADIM + j*16 + lr] = out_acc[j][r] * 0.125f;
    }
}

extern "C" void kernel_launch(void* const* d_in, const int* in_sizes, int n_in,
                              void* d_out, int out_size, void* d_ws, size_t ws_size,
                              hipStream_t stream)
{
  const float* states = (const float*)d_in[0];
  const float* W1  = (const float*)d_in[1];
  const float* b1  = (const float*)d_in[2];
  const float* W2  = (const float*)d_in[3];
  const float* b2  = (const float*)d_in[4];
  const float* W3  = (const float*)d_in[5];
  const float* b3  = (const float*)d_in[6];
  const float* Ws1 = (const float*)d_in[13];
  const float* bs1 = (const float*)d_in[14];
  const float* Ws2 = (const float*)d_in[15];
  const float* bs2 = (const float*)d_in[16];
  const float* Wc1 = (const float*)d_in[17];
  const float* bc1 = (const float*)d_in[18];
  const float* Wc2 = (const float*)d_in[19];
  const float* bc2 = (const float*)d_in[20];

  unsigned short* wbuf = (unsigned short*)d_ws;
  float* b1e = (float*)((char*)d_ws + (size_t)NAG * WAGENT * 2);

  dim3 pb(256), pg((NAG * WAGENT + 255) / 256);
  prep_weights<<<pg, pb, 0, stream>>>(W1, W2, W3, Wc1, Ws1, b1, bc1, bs1, wbuf, b1e);

  dim3 mb(512), mg(BATCH / 128);   // 256 blocks = 1 per CU, 8 waves each
  qatten_main<<<mg, mb, 0, stream>>>(states, b2, b3, Ws2, bs2, Wc2, bc2,
                                     wbuf, b1e, (float*)d_out);
}